// Round 1
// baseline (1701.889 us; speedup 1.0000x reference)
//
#include <hip/hip_runtime.h>
#include <cstdint>

typedef __bf16 bf16;
typedef __attribute__((ext_vector_type(8))) __bf16 bf16x8;
typedef __attribute__((ext_vector_type(4))) __bf16 bf16x4;
typedef __attribute__((ext_vector_type(4))) float f32x4;
typedef __attribute__((ext_vector_type(2))) float f32x2;

static __device__ __forceinline__ float elu1(float x) {
    return x > 0.f ? x : (__expf(x) - 1.f);
}

// ---------------------------------------------------------------------------
// Weight conversion: f32 -> bf16, all weights concatenated into ws, with
// phi1_w1 row-padded 514 -> 544 (zeros) so GEMM fragment loads stay 16B-aligned.
// ---------------------------------------------------------------------------
struct CvtArgs {
    const float* src[13];
    int rows[13];
    int scols[13];
    int dcols[13];
    int total;
};

__global__ void cvt_k(CvtArgs a, bf16* __restrict__ dst) {
    int idx = blockIdx.x * 256 + threadIdx.x;
    if (idx >= a.total) return;
    int rem = idx;
#pragma unroll 1
    for (int s = 0; s < 13; ++s) {
        int sz = a.rows[s] * a.dcols[s];
        if (rem < sz) {
            int r = rem / a.dcols[s];
            int c = rem - r * a.dcols[s];
            float v = (c < a.scols[s]) ? a.src[s][(long)r * a.scols[s] + c] : 0.f;
            dst[idx] = (bf16)v;
            return;
        }
        rem -= sz;
    }
}

// ---------------------------------------------------------------------------
// Universal strip GEMM: C = act(A @ W^T + bias)
// One wave = 16 rows of A, A-strip (full K) held in registers, loops n-tiles.
// MFMA 16x16x32 bf16. A modes: f32 (aligned/unaligned), bf16, or the fused
// alt_val composite enc + km[row/16] - key1*(1/16).
// ---------------------------------------------------------------------------
struct GemmArgs {
    const float* Af;
    const bf16*  Ab;
    long lda;
    const float* enc;    // ALT mode
    const float* km;     // ALT mode
    const bf16*  key1;   // ALT mode
    const bf16*  W;
    long ldw;
    const float* bias;
    bf16*  Cb;
    float* Cf;
    long ldc;
    int gpc;             // n-groups (of 4 tiles = 64 cols) per blockIdx.y
};

enum { AM_F32 = 0, AM_F32U = 1, AM_BF16 = 2, AM_ALT = 3 };
enum { ACT_NONE = 0, ACT_ELU = 1, ACT_ELU2 = 2 };

template <int KF, bool TAIL, int AMODE, int ACT, bool OUTB>
__global__ __launch_bounds__(256, 2) void gemm_k(GemmArgs g) {
    const int lane = threadIdx.x & 63;
    const int wave = threadIdx.x >> 6;
    const int ln   = lane & 15;
    const int quad = lane >> 4;
    const long strip = (long)blockIdx.x * 4 + wave;
    const long row   = strip * 16 + ln;

    constexpr int KFULL = TAIL ? (KF - 1) : KF;
    bf16x8 a[KF];

    if constexpr (AMODE == AM_BF16) {
        const bf16* ap = g.Ab + row * g.lda + quad * 8;
#pragma unroll
        for (int i = 0; i < KFULL; ++i)
            a[i] = *(const bf16x8*)(ap + i * 32);
    } else if constexpr (AMODE == AM_F32) {
        const float* ap = g.Af + row * g.lda + quad * 8;
#pragma unroll
        for (int i = 0; i < KFULL; ++i) {
            f32x4 p0 = *(const f32x4*)(ap + i * 32);
            f32x4 p1 = *(const f32x4*)(ap + i * 32 + 4);
            bf16x8 t;
            t[0] = (bf16)p0.x; t[1] = (bf16)p0.y; t[2] = (bf16)p0.z; t[3] = (bf16)p0.w;
            t[4] = (bf16)p1.x; t[5] = (bf16)p1.y; t[6] = (bf16)p1.z; t[7] = (bf16)p1.w;
            a[i] = t;
        }
    } else if constexpr (AMODE == AM_F32U) {
        // 8B-aligned loads only (lda=514 -> rows not 16B-aligned)
        const float* ap = g.Af + row * g.lda + quad * 8;
#pragma unroll
        for (int i = 0; i < KFULL; ++i) {
            bf16x8 t;
#pragma unroll
            for (int e = 0; e < 8; e += 2) {
                f32x2 p = *(const f32x2*)(ap + i * 32 + e);
                t[e] = (bf16)p.x; t[e + 1] = (bf16)p.y;
            }
            a[i] = t;
        }
    } else {  // AM_ALT: enc + km[group] - key1/16, all lda = 512
        const float* ep = g.enc  + row * 512 + quad * 8;
        const float* mp = g.km   + (row >> 4) * 512 + quad * 8;
        const bf16*  xp = g.key1 + row * 512 + quad * 8;
#pragma unroll
        for (int i = 0; i < KFULL; ++i) {
            f32x4 e0 = *(const f32x4*)(ep + i * 32);
            f32x4 e1 = *(const f32x4*)(ep + i * 32 + 4);
            f32x4 m0 = *(const f32x4*)(mp + i * 32);
            f32x4 m1 = *(const f32x4*)(mp + i * 32 + 4);
            bf16x8 x8 = *(const bf16x8*)(xp + i * 32);
            bf16x8 t;
            t[0] = (bf16)(e0.x + m0.x - (float)x8[0] * 0.0625f);
            t[1] = (bf16)(e0.y + m0.y - (float)x8[1] * 0.0625f);
            t[2] = (bf16)(e0.z + m0.z - (float)x8[2] * 0.0625f);
            t[3] = (bf16)(e0.w + m0.w - (float)x8[3] * 0.0625f);
            t[4] = (bf16)(e1.x + m1.x - (float)x8[4] * 0.0625f);
            t[5] = (bf16)(e1.y + m1.y - (float)x8[5] * 0.0625f);
            t[6] = (bf16)(e1.z + m1.z - (float)x8[6] * 0.0625f);
            t[7] = (bf16)(e1.w + m1.w - (float)x8[7] * 0.0625f);
            a[i] = t;
        }
    }
    if constexpr (TAIL) {  // K=514: frag 16 holds k=512,513 in quad 0 only
        bf16x8 t;
#pragma unroll
        for (int e = 0; e < 8; ++e) t[e] = (bf16)0.f;
        if (quad == 0) {
            const float* ap = g.Af + row * g.lda + (KF - 1) * 32;
            f32x2 p = *(const f32x2*)ap;
            t[0] = (bf16)p.x; t[1] = (bf16)p.y;
        }
        a[KF - 1] = t;
    }

    const int ngbase = blockIdx.y * g.gpc;
    for (int grp = 0; grp < g.gpc; ++grp) {
        const int nt0 = (ngbase + grp) * 4;
        const bf16* w0 = g.W + (long)(nt0 * 16 + ln) * g.ldw + quad * 8;
        const bf16* w1 = w0 + 16 * g.ldw;
        const bf16* w2 = w1 + 16 * g.ldw;
        const bf16* w3 = w2 + 16 * g.ldw;
        f32x4 c0 = {0.f, 0.f, 0.f, 0.f}, c1 = c0, c2 = c0, c3 = c0;
#pragma unroll
        for (int i = 0; i < KF; ++i) {
            bf16x8 b0 = *(const bf16x8*)(w0 + i * 32);
            bf16x8 b1 = *(const bf16x8*)(w1 + i * 32);
            bf16x8 b2 = *(const bf16x8*)(w2 + i * 32);
            bf16x8 b3 = *(const bf16x8*)(w3 + i * 32);
            c0 = __builtin_amdgcn_mfma_f32_16x16x32_bf16(a[i], b0, c0, 0, 0, 0);
            c1 = __builtin_amdgcn_mfma_f32_16x16x32_bf16(a[i], b1, c1, 0, 0, 0);
            c2 = __builtin_amdgcn_mfma_f32_16x16x32_bf16(a[i], b2, c2, 0, 0, 0);
            c3 = __builtin_amdgcn_mfma_f32_16x16x32_bf16(a[i], b3, c3, 0, 0, 0);
        }
        const long rowbase = strip * 16 + quad * 4;
        f32x4 cc[4] = {c0, c1, c2, c3};
#pragma unroll
        for (int t = 0; t < 4; ++t) {
            const int n = (nt0 + t) * 16 + ln;
            const float bv = g.bias[n];
#pragma unroll
            for (int r = 0; r < 4; ++r) {
                float v = cc[t][r] + bv;
                if constexpr (ACT >= ACT_ELU) v = elu1(v);
                if constexpr (ACT == ACT_ELU2) v = elu1(v);
                const long o = (rowbase + r) * g.ldc + n;
                if constexpr (OUTB) g.Cb[o] = (bf16)v;
                else                g.Cf[o] = v;
            }
        }
    }
}

// ---------------------------------------------------------------------------
// Per-group attention: one wave per (group, head). Computes
// obar[g] = mean_i softmax_j(q_i.k_j/16) @ V  directly (mean folded in).
// Lane layout: i = lane&15 (query row), jb = (lane>>4)*4 (4 key cols).
// ---------------------------------------------------------------------------
__global__ __launch_bounds__(256) void attn_k(const bf16* __restrict__ qkv,
                                              bf16* __restrict__ obar,
                                              int ngroups) {
    const int tid = blockIdx.x * 256 + threadIdx.x;
    const int wv = tid >> 6;
    const int g  = wv >> 1;
    const int h  = wv & 1;
    if (g >= ngroups) return;
    const int lane = threadIdx.x & 63;
    const int i  = lane & 15;
    const int jb = (lane >> 4) << 2;

    const bf16* base  = qkv + (long)g * 16 * 1536;
    const bf16* qrow  = base + (long)i * 1536 + h * 256;
    const bf16* kbase = base + 512 + h * 256;

    float s0 = 0.f, s1 = 0.f, s2 = 0.f, s3 = 0.f;
    for (int kk = 0; kk < 256; kk += 8) {
        bf16x8 qv = *(const bf16x8*)(qrow + kk);
        float qf[8];
#pragma unroll
        for (int e = 0; e < 8; ++e) qf[e] = (float)qv[e];
        bf16x8 k0 = *(const bf16x8*)(kbase + (long)(jb + 0) * 1536 + kk);
        bf16x8 k1 = *(const bf16x8*)(kbase + (long)(jb + 1) * 1536 + kk);
        bf16x8 k2 = *(const bf16x8*)(kbase + (long)(jb + 2) * 1536 + kk);
        bf16x8 k3 = *(const bf16x8*)(kbase + (long)(jb + 3) * 1536 + kk);
#pragma unroll
        for (int e = 0; e < 8; ++e) {
            s0 += qf[e] * (float)k0[e];
            s1 += qf[e] * (float)k1[e];
            s2 += qf[e] * (float)k2[e];
            s3 += qf[e] * (float)k3[e];
        }
    }
    const float sc = 1.f / 16.f;  // 1/sqrt(dh), dh=256
    s0 *= sc; s1 *= sc; s2 *= sc; s3 *= sc;
    float m = fmaxf(fmaxf(s0, s1), fmaxf(s2, s3));
    m = fmaxf(m, __shfl_xor(m, 16));
    m = fmaxf(m, __shfl_xor(m, 32));
    float e0 = __expf(s0 - m), e1 = __expf(s1 - m), e2 = __expf(s2 - m), e3 = __expf(s3 - m);
    float rs = e0 + e1 + e2 + e3;
    rs += __shfl_xor(rs, 16);
    rs += __shfl_xor(rs, 32);
    const float inv = 1.f / (rs * 16.f);  // row-normalize + mean over i
    float cb[4] = {e0 * inv, e1 * inv, e2 * inv, e3 * inv};
#pragma unroll
    for (int msk = 1; msk <= 8; msk <<= 1) {
        cb[0] += __shfl_xor(cb[0], msk);
        cb[1] += __shfl_xor(cb[1], msk);
        cb[2] += __shfl_xor(cb[2], msk);
        cb[3] += __shfl_xor(cb[3], msk);
    }
    float call[16];
#pragma unroll
    for (int j = 0; j < 16; ++j)
        call[j] = __shfl(cb[j & 3], (j >> 2) << 4);

    const int d0 = lane << 2;  // 4 output dims per lane
    const bf16* vb = base + 1024 + h * 256 + d0;
    float o0 = 0.f, o1 = 0.f, o2 = 0.f, o3 = 0.f;
#pragma unroll
    for (int j = 0; j < 16; ++j) {
        bf16x4 vv = *(const bf16x4*)(vb + (long)j * 1536);
        o0 += call[j] * (float)vv[0];
        o1 += call[j] * (float)vv[1];
        o2 += call[j] * (float)vv[2];
        o3 += call[j] * (float)vv[3];
    }
    bf16x4 ov;
    ov[0] = (bf16)o0; ov[1] = (bf16)o1; ov[2] = (bf16)o2; ov[3] = (bf16)o3;
    *(bf16x4*)(obar + (long)g * 512 + h * 256 + d0) = ov;
}

// q_jt = hg3 @ g_w4^T + g_b4  (4096 x 1)
__global__ void qjt_k(const bf16* __restrict__ hg, const bf16* __restrict__ w,
                      const float* __restrict__ b, float* __restrict__ out) {
    const int m = blockIdx.x * 256 + threadIdx.x;
    const bf16* hp = hg + (long)m * 256;
    float acc = 0.f;
    for (int k = 0; k < 256; k += 8) {
        bf16x8 hv = *(const bf16x8*)(hp + k);
        bf16x8 wv = *(const bf16x8*)(w + k);
#pragma unroll
        for (int e = 0; e < 8; ++e) acc += (float)hv[e] * (float)wv[e];
    }
    out[m] = acc + b[0];
}

// alt_q = hp2 @ phi2_w3^T + phi2_b3  (65536 x 2)
__global__ void altq_k(const bf16* __restrict__ hp, const bf16* __restrict__ w,
                       const float* __restrict__ b, float* __restrict__ out) {
    const int m = blockIdx.x * 256 + threadIdx.x;
    const bf16* hr = hp + (long)m * 256;
    float a0 = 0.f, a1 = 0.f;
    for (int k = 0; k < 256; k += 8) {
        bf16x8 hv = *(const bf16x8*)(hr + k);
        bf16x8 w0 = *(const bf16x8*)(w + k);
        bf16x8 w1 = *(const bf16x8*)(w + 256 + k);
#pragma unroll
        for (int e = 0; e < 8; ++e) {
            float hf = (float)hv[e];
            a0 += hf * (float)w0[e];
            a1 += hf * (float)w1[e];
        }
    }
    out[2 * m]     = a0 + b[0];
    out[2 * m + 1] = a1 + b[1];
}

// ---------------------------------------------------------------------------
extern "C" void kernel_launch(void* const* d_in, const int* in_sizes, int n_in,
                              void* d_out, int out_size, void* d_ws, size_t ws_size,
                              hipStream_t stream) {
    const float* enc    = (const float*)d_in[0];
    const float* encA   = (const float*)d_in[1];
    const float* w_ain  = (const float*)d_in[2];
    const float* b_ain  = (const float*)d_in[3];
    const float* w_aout = (const float*)d_in[4];
    const float* b_aout = (const float*)d_in[5];
    const float* w_p11  = (const float*)d_in[6];
    const float* b_p11  = (const float*)d_in[7];
    const float* w_p12  = (const float*)d_in[8];
    const float* b_p12  = (const float*)d_in[9];
    const float* w_p13  = (const float*)d_in[10];
    const float* b_p13  = (const float*)d_in[11];
    const float* w_p14  = (const float*)d_in[12];
    const float* b_p14  = (const float*)d_in[13];
    const float* w_g1   = (const float*)d_in[14];
    const float* b_g1   = (const float*)d_in[15];
    const float* w_g2   = (const float*)d_in[16];
    const float* b_g2   = (const float*)d_in[17];
    const float* w_g3   = (const float*)d_in[18];
    const float* b_g3   = (const float*)d_in[19];
    const float* w_g4   = (const float*)d_in[20];
    const float* b_g4   = (const float*)d_in[21];
    const float* w_p21  = (const float*)d_in[22];
    const float* b_p21  = (const float*)d_in[23];
    const float* w_p22  = (const float*)d_in[24];
    const float* b_p22  = (const float*)d_in[25];
    const float* w_p23  = (const float*)d_in[26];
    const float* b_p23  = (const float*)d_in[27];
    float* out = (float*)d_out;

    // ---- workspace layout ----
    char* wsc = (char*)d_ws;
    size_t off = 0;
    auto take = [&](size_t bytes) -> char* {
        char* p = wsc + off;
        off += (bytes + 255) & ~(size_t)255;
        return p;
    };

    // weight bf16 region (contiguous, cvt order)
    const long o_ain  = 0;
    const long o_aout = o_ain + 1536L * 512;
    const long o_p11  = o_aout + 512L * 512;
    const long o_p12  = o_p11 + 256L * 544;   // padded 514->544
    const long o_p13  = o_p12 + 256L * 256;
    const long o_p14  = o_p13 + 256L * 256;
    const long o_g1   = o_p14 + 512L * 256;
    const long o_g2   = o_g1 + 256L * 512;
    const long o_g3   = o_g2 + 256L * 256;
    const long o_g4   = o_g3 + 256L * 256;
    const long o_p21  = o_g4 + 256L;
    const long o_p22  = o_p21 + 256L * 512;
    const long o_p23  = o_p22 + 256L * 256;
    const long wtot   = o_p23 + 2L * 256;     // 1,909,504 elements

    bf16*  wb  = (bf16*)take((size_t)wtot * 2);
    bf16*  Ha  = (bf16*)take(65536ull * 256 * 2);
    bf16*  Hb  = (bf16*)take(65536ull * 256 * 2);
    bf16*  K1  = (bf16*)take(65536ull * 512 * 2);
    bf16*  OB  = (bf16*)take(4096ull * 512 * 2);
    float* KM  = (float*)take(4096ull * 512 * 4);
    bf16*  HGa = (bf16*)take(4096ull * 256 * 2);
    bf16*  HGb = (bf16*)take(4096ull * 256 * 2);

    // attention chunking: smallest chunk count whose qkv buffer fits
    int CH = 16;
    if (off + (65536ull / 2) * 1536 * 2 <= ws_size)      CH = 2;
    else if (off + (65536ull / 4) * 1536 * 2 <= ws_size) CH = 4;
    else if (off + (65536ull / 8) * 1536 * 2 <= ws_size) CH = 8;
    bf16* QKV = (bf16*)take((size_t)(65536 / CH) * 1536 * 2);

    // ---- 1. convert weights ----
    CvtArgs ca;
    const float* srcs[13] = {w_ain, w_aout, w_p11, w_p12, w_p13, w_p14,
                             w_g1, w_g2, w_g3, w_g4, w_p21, w_p22, w_p23};
    const int rows_[13]  = {1536, 512, 256, 256, 256, 512, 256, 256, 256, 1, 256, 256, 2};
    const int scols_[13] = {512, 512, 514, 256, 256, 256, 512, 256, 256, 256, 512, 256, 256};
    const int dcols_[13] = {512, 512, 544, 256, 256, 256, 512, 256, 256, 256, 512, 256, 256};
    for (int s = 0; s < 13; ++s) {
        ca.src[s] = srcs[s]; ca.rows[s] = rows_[s];
        ca.scols[s] = scols_[s]; ca.dcols[s] = dcols_[s];
    }
    ca.total = (int)wtot;
    cvt_k<<<dim3((unsigned)((wtot + 255) / 256)), dim3(256), 0, stream>>>(ca, wb);

    GemmArgs ga;

    // ---- 2. phi1 chain ----
    ga = {}; ga.Af = encA; ga.lda = 514; ga.W = wb + o_p11; ga.ldw = 544;
    ga.bias = b_p11; ga.Cb = Ha; ga.ldc = 256; ga.gpc = 4;
    gemm_k<17, true, AM_F32U, ACT_ELU, true><<<dim3(1024, 1), 256, 0, stream>>>(ga);

    ga = {}; ga.Ab = Ha; ga.lda = 256; ga.W = wb + o_p12; ga.ldw = 256;
    ga.bias = b_p12; ga.Cb = Hb; ga.ldc = 256; ga.gpc = 4;
    gemm_k<8, false, AM_BF16, ACT_ELU2, true><<<dim3(1024, 1), 256, 0, stream>>>(ga);

    ga = {}; ga.Ab = Hb; ga.lda = 256; ga.W = wb + o_p13; ga.ldw = 256;
    ga.bias = b_p13; ga.Cb = Ha; ga.ldc = 256; ga.gpc = 4;
    gemm_k<8, false, AM_BF16, ACT_ELU, true><<<dim3(1024, 1), 256, 0, stream>>>(ga);

    ga = {}; ga.Ab = Ha; ga.lda = 256; ga.W = wb + o_p14; ga.ldw = 256;
    ga.bias = b_p14; ga.Cb = K1; ga.ldc = 512; ga.gpc = 8;
    gemm_k<8, false, AM_BF16, ACT_NONE, true><<<dim3(1024, 1), 256, 0, stream>>>(ga);

    // ---- 3. chunked qkv + attention ----
    const int Mc = 65536 / CH;  // rows per chunk
    const int gc = 4096 / CH;   // groups per chunk
    for (int c = 0; c < CH; ++c) {
        ga = {}; ga.Ab = K1 + (long)c * Mc * 512; ga.lda = 512;
        ga.W = wb + o_ain; ga.ldw = 512; ga.bias = b_ain;
        ga.Cb = QKV; ga.ldc = 1536; ga.gpc = 6;
        gemm_k<16, false, AM_BF16, ACT_NONE, true>
            <<<dim3(Mc / 64, 4), 256, 0, stream>>>(ga);
        attn_k<<<dim3((gc * 2) / 4), 256, 0, stream>>>(QKV, OB + (long)c * gc * 512, gc);
    }

    // ---- 4. key1_mean = obar @ attn_out_w^T + b (f32) ----
    ga = {}; ga.Ab = OB; ga.lda = 512; ga.W = wb + o_aout; ga.ldw = 512;
    ga.bias = b_aout; ga.Cf = KM; ga.ldc = 512; ga.gpc = 2;
    gemm_k<16, false, AM_BF16, ACT_NONE, false><<<dim3(64, 4), 256, 0, stream>>>(ga);

    // ---- 5. g head ----
    ga = {}; ga.Af = KM; ga.lda = 512; ga.W = wb + o_g1; ga.ldw = 512;
    ga.bias = b_g1; ga.Cb = HGa; ga.ldc = 256; ga.gpc = 1;
    gemm_k<16, false, AM_F32, ACT_ELU, true><<<dim3(64, 4), 256, 0, stream>>>(ga);

    ga = {}; ga.Ab = HGa; ga.lda = 256; ga.W = wb + o_g2; ga.ldw = 256;
    ga.bias = b_g2; ga.Cb = HGb; ga.ldc = 256; ga.gpc = 1;
    gemm_k<8, false, AM_BF16, ACT_ELU, true><<<dim3(64, 4), 256, 0, stream>>>(ga);

    ga = {}; ga.Ab = HGb; ga.lda = 256; ga.W = wb + o_g3; ga.ldw = 256;
    ga.bias = b_g3; ga.Cb = HGa; ga.ldc = 256; ga.gpc = 1;
    gemm_k<8, false, AM_BF16, ACT_ELU, true><<<dim3(64, 4), 256, 0, stream>>>(ga);

    qjt_k<<<dim3(16), 256, 0, stream>>>(HGa, wb + o_g4, b_g4, out);

    // ---- 6. phi2 chain (alt_val fused into A-load) ----
    ga = {}; ga.enc = enc; ga.km = KM; ga.key1 = K1;
    ga.W = wb + o_p21; ga.ldw = 512; ga.bias = b_p21;
    ga.Cb = Ha; ga.ldc = 256; ga.gpc = 4;
    gemm_k<16, false, AM_ALT, ACT_ELU, true><<<dim3(1024, 1), 256, 0, stream>>>(ga);

    ga = {}; ga.Ab = Ha; ga.lda = 256; ga.W = wb + o_p22; ga.ldw = 256;
    ga.bias = b_p22; ga.Cb = Hb; ga.ldc = 256; ga.gpc = 4;
    gemm_k<8, false, AM_BF16, ACT_ELU, true><<<dim3(1024, 1), 256, 0, stream>>>(ga);

    altq_k<<<dim3(256), 256, 0, stream>>>(Hb, wb + o_p23, b_p23, out + 4096);
}

// Round 2
// 789.332 us; speedup vs baseline: 2.1561x; 2.1561x over previous
//
#include <hip/hip_runtime.h>
#include <cstdint>

typedef __bf16 bf16;
typedef __attribute__((ext_vector_type(8))) __bf16 bf16x8;
typedef __attribute__((ext_vector_type(4))) __bf16 bf16x4;
typedef __attribute__((ext_vector_type(4))) float f32x4;
typedef __attribute__((ext_vector_type(2))) float f32x2;

static __device__ __forceinline__ float elu1(float x) {
    return x > 0.f ? x : (__expf(x) - 1.f);
}

// global -> LDS async copy, 16 B per lane. LDS dest must be wave-uniform
// base + lane*16 (pass per-lane ptr; lane 0's value is the base).
static __device__ __forceinline__ void gl_lds16(const void* gp, void* lp) {
    __builtin_amdgcn_global_load_lds(
        (const __attribute__((address_space(1))) void*)(uintptr_t)gp,
        (__attribute__((address_space(3))) void*)(uint32_t)(uintptr_t)lp,
        16, 0, 0);
}

// ---------------------------------------------------------------------------
// Weight conversion: f32 -> bf16, all weights concatenated into ws, with
// phi1_w1 row-padded 514 -> 576 (zeros) so K-steps stay 64-wide.
// ---------------------------------------------------------------------------
struct CvtArgs {
    const float* src[13];
    int rows[13];
    int scols[13];
    int dcols[13];
    int total;
};

__global__ void cvt_k(CvtArgs a, bf16* __restrict__ dst) {
    int idx = blockIdx.x * 256 + threadIdx.x;
    if (idx >= a.total) return;
    int rem = idx;
#pragma unroll 1
    for (int s = 0; s < 13; ++s) {
        int sz = a.rows[s] * a.dcols[s];
        if (rem < sz) {
            int r = rem / a.dcols[s];
            int c = rem - r * a.dcols[s];
            float v = (c < a.scols[s]) ? a.src[s][(long)r * a.scols[s] + c] : 0.f;
            dst[idx] = (bf16)v;
            return;
        }
        rem -= sz;
    }
}

// ---------------------------------------------------------------------------
// Tiled GEMM (m97 structure): C = act(A @ W^T + bias)
// 128x128 block tile, BK=64, 256 threads = 4 waves, each wave 64x64
// (4x4 grid of 16x16x32 MFMA). LDS staged via global_load_lds (bf16
// operands) or VALU compose + ds_write (f32 / fused alt_val A).
// Swizzled LDS layout: 16B chunk p of row m stored at slot (p+m)&7.
// ---------------------------------------------------------------------------
struct GemmArgs {
    const float* Af;
    const bf16*  Ab;
    long lda;
    const float* enc;    // ALT mode
    const float* km;     // ALT mode
    const bf16*  key1;   // ALT mode
    const bf16*  W;
    long ldw;
    const float* bias;
    bf16*  Cb;
    float* Cf;
    long ldc;
    int nK;              // number of 64-wide K-steps
    int klim;            // valid A cols (F32U bounds)
};

enum { AM_F32 = 0, AM_F32U = 1, AM_BF16 = 2, AM_ALT = 3 };
enum { ACT_NONE = 0, ACT_ELU = 1, ACT_ELU2 = 2 };

template <int AMODE, int ACT, bool OUTB>
__global__ __launch_bounds__(256, 2) void gemm_t(GemmArgs g) {
    __shared__ bf16 As[128 * 64];
    __shared__ bf16 Bs[128 * 64];

    const int tid  = threadIdx.x;
    const int wave = tid >> 6;
    const int lane = tid & 63;
    const int ln   = lane & 15;
    const int quad = lane >> 4;

    const long m0 = (long)blockIdx.x * 128;
    const long n0 = (long)blockIdx.y * 128;
    const int  wm = (wave & 1) * 64;
    const int  wn = (wave >> 1) * 64;

    f32x4 acc[4][4] = {};

    for (int ks = 0; ks < g.nK; ++ks) {
        const int k0 = ks * 64;
        __syncthreads();

        // ---- stage A (128 rows x 64 cols = 1024 16B chunks) ----
        if constexpr (AMODE == AM_BF16) {
            const int cbase = wave * 256;
#pragma unroll
            for (int r = 0; r < 4; ++r) {
                const int c = cbase + r * 64 + lane;
                const int m = c >> 3, s = c & 7;
                const int pg = (s - m) & 7;
                gl_lds16(g.Ab + (m0 + m) * g.lda + k0 + pg * 8, &As[c * 8]);
            }
        } else {
#pragma unroll
            for (int r = 0; r < 4; ++r) {
                const int c = r * 256 + tid;
                const int m = c >> 3, s = c & 7;
                const int pg = (s - m) & 7;
                const int kk = k0 + pg * 8;
                bf16x8 t;
                if constexpr (AMODE == AM_F32) {
                    const float* ap = g.Af + (m0 + m) * g.lda + kk;
                    f32x4 p0 = *(const f32x4*)ap;
                    f32x4 p1 = *(const f32x4*)(ap + 4);
                    t[0] = (bf16)p0.x; t[1] = (bf16)p0.y; t[2] = (bf16)p0.z; t[3] = (bf16)p0.w;
                    t[4] = (bf16)p1.x; t[5] = (bf16)p1.y; t[6] = (bf16)p1.z; t[7] = (bf16)p1.w;
                } else if constexpr (AMODE == AM_F32U) {
                    const float* ap = g.Af + (m0 + m) * g.lda;
                    if (kk + 8 <= g.klim) {
#pragma unroll
                        for (int e = 0; e < 8; e += 2) {
                            f32x2 p = *(const f32x2*)(ap + kk + e);
                            t[e] = (bf16)p.x; t[e + 1] = (bf16)p.y;
                        }
                    } else {
#pragma unroll
                        for (int e = 0; e < 8; ++e) {
                            const int col = kk + e;
                            t[e] = (bf16)(col < g.klim ? ap[col] : 0.f);
                        }
                    }
                } else {  // AM_ALT: enc + km[row/16] - key1/16
                    const long row = m0 + m;
                    const float* ep = g.enc + row * 512 + kk;
                    const float* mp = g.km + (row >> 4) * 512 + kk;
                    const bf16*  xp = g.key1 + row * 512 + kk;
                    f32x4 e0 = *(const f32x4*)ep;
                    f32x4 e1 = *(const f32x4*)(ep + 4);
                    f32x4 q0 = *(const f32x4*)mp;
                    f32x4 q1 = *(const f32x4*)(mp + 4);
                    bf16x8 x8 = *(const bf16x8*)xp;
                    t[0] = (bf16)(e0.x + q0.x - (float)x8[0] * 0.0625f);
                    t[1] = (bf16)(e0.y + q0.y - (float)x8[1] * 0.0625f);
                    t[2] = (bf16)(e0.z + q0.z - (float)x8[2] * 0.0625f);
                    t[3] = (bf16)(e0.w + q0.w - (float)x8[3] * 0.0625f);
                    t[4] = (bf16)(e1.x + q1.x - (float)x8[4] * 0.0625f);
                    t[5] = (bf16)(e1.y + q1.y - (float)x8[5] * 0.0625f);
                    t[6] = (bf16)(e1.z + q1.z - (float)x8[6] * 0.0625f);
                    t[7] = (bf16)(e1.w + q1.w - (float)x8[7] * 0.0625f);
                }
                *(bf16x8*)(&As[m * 64 + s * 8]) = t;
            }
        }

        // ---- stage B ----
        {
            const int cbase = wave * 256;
#pragma unroll
            for (int r = 0; r < 4; ++r) {
                const int c = cbase + r * 64 + lane;
                const int n = c >> 3, s = c & 7;
                const int pg = (s - n) & 7;
                gl_lds16(g.W + (n0 + n) * g.ldw + k0 + pg * 8, &Bs[c * 8]);
            }
        }
        __syncthreads();

        // ---- compute: 2 k-subs x 16 MFMA ----
#pragma unroll
        for (int ksub = 0; ksub < 2; ++ksub) {
            bf16x8 av[4], bv[4];
#pragma unroll
            for (int t = 0; t < 4; ++t) {
                const int m = wm + t * 16 + ln;
                const int sa = ((ksub * 4 + quad) + m) & 7;
                av[t] = *(const bf16x8*)(&As[m * 64 + sa * 8]);
                const int n = wn + t * 16 + ln;
                const int sb = ((ksub * 4 + quad) + n) & 7;
                bv[t] = *(const bf16x8*)(&Bs[n * 64 + sb * 8]);
            }
#pragma unroll
            for (int i = 0; i < 4; ++i)
#pragma unroll
                for (int j = 0; j < 4; ++j)
                    acc[i][j] = __builtin_amdgcn_mfma_f32_16x16x32_bf16(
                        av[i], bv[j], acc[i][j], 0, 0, 0);
        }
    }

    // ---- epilogue ----
#pragma unroll
    for (int i = 0; i < 4; ++i) {
        const long rb = m0 + wm + i * 16 + quad * 4;
#pragma unroll
        for (int j = 0; j < 4; ++j) {
            const long n = n0 + wn + j * 16 + ln;
            const float bvs = g.bias[n];
#pragma unroll
            for (int r = 0; r < 4; ++r) {
                float v = acc[i][j][r] + bvs;
                if constexpr (ACT >= ACT_ELU) v = elu1(v);
                if constexpr (ACT == ACT_ELU2) v = elu1(v);
                const long o = (rb + r) * g.ldc + n;
                if constexpr (OUTB) g.Cb[o] = (bf16)v;
                else                g.Cf[o] = v;
            }
        }
    }
}

// ---------------------------------------------------------------------------
// Per-group attention: one wave per (group, head). Computes
// obar[g] = mean_i softmax_j(q_i.k_j/16) @ V  directly (mean folded in).
// ---------------------------------------------------------------------------
__global__ __launch_bounds__(256) void attn_k(const bf16* __restrict__ qkv,
                                              bf16* __restrict__ obar,
                                              int ngroups) {
    const int tid = blockIdx.x * 256 + threadIdx.x;
    const int wv = tid >> 6;
    const int g  = wv >> 1;
    const int h  = wv & 1;
    if (g >= ngroups) return;
    const int lane = threadIdx.x & 63;
    const int i  = lane & 15;
    const int jb = (lane >> 4) << 2;

    const bf16* base  = qkv + (long)g * 16 * 1536;
    const bf16* qrow  = base + (long)i * 1536 + h * 256;
    const bf16* kbase = base + 512 + h * 256;

    float s0 = 0.f, s1 = 0.f, s2 = 0.f, s3 = 0.f;
    for (int kk = 0; kk < 256; kk += 8) {
        bf16x8 qv = *(const bf16x8*)(qrow + kk);
        float qf[8];
#pragma unroll
        for (int e = 0; e < 8; ++e) qf[e] = (float)qv[e];
        bf16x8 k0 = *(const bf16x8*)(kbase + (long)(jb + 0) * 1536 + kk);
        bf16x8 k1 = *(const bf16x8*)(kbase + (long)(jb + 1) * 1536 + kk);
        bf16x8 k2 = *(const bf16x8*)(kbase + (long)(jb + 2) * 1536 + kk);
        bf16x8 k3 = *(const bf16x8*)(kbase + (long)(jb + 3) * 1536 + kk);
#pragma unroll
        for (int e = 0; e < 8; ++e) {
            s0 += qf[e] * (float)k0[e];
            s1 += qf[e] * (float)k1[e];
            s2 += qf[e] * (float)k2[e];
            s3 += qf[e] * (float)k3[e];
        }
    }
    const float sc = 1.f / 16.f;  // 1/sqrt(dh), dh=256
    s0 *= sc; s1 *= sc; s2 *= sc; s3 *= sc;
    float m = fmaxf(fmaxf(s0, s1), fmaxf(s2, s3));
    m = fmaxf(m, __shfl_xor(m, 16));
    m = fmaxf(m, __shfl_xor(m, 32));
    float e0 = __expf(s0 - m), e1 = __expf(s1 - m), e2 = __expf(s2 - m), e3 = __expf(s3 - m);
    float rs = e0 + e1 + e2 + e3;
    rs += __shfl_xor(rs, 16);
    rs += __shfl_xor(rs, 32);
    const float inv = 1.f / (rs * 16.f);  // row-normalize + mean over i
    float cb[4] = {e0 * inv, e1 * inv, e2 * inv, e3 * inv};
#pragma unroll
    for (int msk = 1; msk <= 8; msk <<= 1) {
        cb[0] += __shfl_xor(cb[0], msk);
        cb[1] += __shfl_xor(cb[1], msk);
        cb[2] += __shfl_xor(cb[2], msk);
        cb[3] += __shfl_xor(cb[3], msk);
    }
    float call[16];
#pragma unroll
    for (int j = 0; j < 16; ++j)
        call[j] = __shfl(cb[j & 3], (j >> 2) << 4);

    const int d0 = lane << 2;
    const bf16* vb = base + 1024 + h * 256 + d0;
    float o0 = 0.f, o1 = 0.f, o2 = 0.f, o3 = 0.f;
#pragma unroll
    for (int j = 0; j < 16; ++j) {
        bf16x4 vv = *(const bf16x4*)(vb + (long)j * 1536);
        o0 += call[j] * (float)vv[0];
        o1 += call[j] * (float)vv[1];
        o2 += call[j] * (float)vv[2];
        o3 += call[j] * (float)vv[3];
    }
    bf16x4 ov;
    ov[0] = (bf16)o0; ov[1] = (bf16)o1; ov[2] = (bf16)o2; ov[3] = (bf16)o3;
    *(bf16x4*)(obar + (long)g * 512 + h * 256 + d0) = ov;
}

// q_jt = hg3 @ g_w4^T + g_b4  (4096 x 1)
__global__ void qjt_k(const bf16* __restrict__ hg, const bf16* __restrict__ w,
                      const float* __restrict__ b, float* __restrict__ out) {
    const int m = blockIdx.x * 256 + threadIdx.x;
    const bf16* hp = hg + (long)m * 256;
    float acc = 0.f;
    for (int k = 0; k < 256; k += 8) {
        bf16x8 hv = *(const bf16x8*)(hp + k);
        bf16x8 wv = *(const bf16x8*)(w + k);
#pragma unroll
        for (int e = 0; e < 8; ++e) acc += (float)hv[e] * (float)wv[e];
    }
    out[m] = acc + b[0];
}

// alt_q = hp2 @ phi2_w3^T + phi2_b3  (65536 x 2)
__global__ void altq_k(const bf16* __restrict__ hp, const bf16* __restrict__ w,
                       const float* __restrict__ b, float* __restrict__ out) {
    const int m = blockIdx.x * 256 + threadIdx.x;
    const bf16* hr = hp + (long)m * 256;
    float a0 = 0.f, a1 = 0.f;
    for (int k = 0; k < 256; k += 8) {
        bf16x8 hv = *(const bf16x8*)(hr + k);
        bf16x8 w0 = *(const bf16x8*)(w + k);
        bf16x8 w1 = *(const bf16x8*)(w + 256 + k);
#pragma unroll
        for (int e = 0; e < 8; ++e) {
            float hf = (float)hv[e];
            a0 += hf * (float)w0[e];
            a1 += hf * (float)w1[e];
        }
    }
    out[2 * m]     = a0 + b[0];
    out[2 * m + 1] = a1 + b[1];
}

// ---------------------------------------------------------------------------
extern "C" void kernel_launch(void* const* d_in, const int* in_sizes, int n_in,
                              void* d_out, int out_size, void* d_ws, size_t ws_size,
                              hipStream_t stream) {
    const float* enc    = (const float*)d_in[0];
    const float* encA   = (const float*)d_in[1];
    const float* w_ain  = (const float*)d_in[2];
    const float* b_ain  = (const float*)d_in[3];
    const float* w_aout = (const float*)d_in[4];
    const float* b_aout = (const float*)d_in[5];
    const float* w_p11  = (const float*)d_in[6];
    const float* b_p11  = (const float*)d_in[7];
    const float* w_p12  = (const float*)d_in[8];
    const float* b_p12  = (const float*)d_in[9];
    const float* w_p13  = (const float*)d_in[10];
    const float* b_p13  = (const float*)d_in[11];
    const float* w_p14  = (const float*)d_in[12];
    const float* b_p14  = (const float*)d_in[13];
    const float* w_g1   = (const float*)d_in[14];
    const float* b_g1   = (const float*)d_in[15];
    const float* w_g2   = (const float*)d_in[16];
    const float* b_g2   = (const float*)d_in[17];
    const float* w_g3   = (const float*)d_in[18];
    const float* b_g3   = (const float*)d_in[19];
    const float* w_g4   = (const float*)d_in[20];
    const float* b_g4   = (const float*)d_in[21];
    const float* w_p21  = (const float*)d_in[22];
    const float* b_p21  = (const float*)d_in[23];
    const float* w_p22  = (const float*)d_in[24];
    const float* b_p22  = (const float*)d_in[25];
    const float* w_p23  = (const float*)d_in[26];
    const float* b_p23  = (const float*)d_in[27];
    float* out = (float*)d_out;

    // ---- workspace layout ----
    char* wsc = (char*)d_ws;
    size_t off = 0;
    auto take = [&](size_t bytes) -> char* {
        char* p = wsc + off;
        off += (bytes + 255) & ~(size_t)255;
        return p;
    };

    // weight bf16 region (contiguous, cvt order); p11 padded 514->576
    const long o_ain  = 0;
    const long o_aout = o_ain + 1536L * 512;
    const long o_p11  = o_aout + 512L * 512;
    const long o_p12  = o_p11 + 256L * 576;
    const long o_p13  = o_p12 + 256L * 256;
    const long o_p14  = o_p13 + 256L * 256;
    const long o_g1   = o_p14 + 512L * 256;
    const long o_g2   = o_g1 + 256L * 512;
    const long o_g3   = o_g2 + 256L * 256;
    const long o_g4   = o_g3 + 256L * 256;
    const long o_p21  = o_g4 + 256L;
    const long o_p22  = o_p21 + 256L * 512;
    const long o_p23  = o_p22 + 256L * 256;
    const long wtot   = o_p23 + 2L * 256;

    bf16*  wb  = (bf16*)take((size_t)wtot * 2);
    bf16*  Ha  = (bf16*)take(65536ull * 256 * 2);
    bf16*  Hb  = (bf16*)take(65536ull * 256 * 2);
    bf16*  K1  = (bf16*)take(65536ull * 512 * 2);
    bf16*  OB  = (bf16*)take(4096ull * 512 * 2);
    float* KM  = (float*)take(4096ull * 512 * 4);
    bf16*  HGa = (bf16*)take(4096ull * 256 * 2);
    bf16*  HGb = (bf16*)take(4096ull * 256 * 2);

    int CH = 16;
    if (off + (65536ull / 2) * 1536 * 2 <= ws_size)      CH = 2;
    else if (off + (65536ull / 4) * 1536 * 2 <= ws_size) CH = 4;
    else if (off + (65536ull / 8) * 1536 * 2 <= ws_size) CH = 8;
    bf16* QKV = (bf16*)take((size_t)(65536 / CH) * 1536 * 2);

    // ---- 1. convert weights ----
    CvtArgs ca;
    const float* srcs[13] = {w_ain, w_aout, w_p11, w_p12, w_p13, w_p14,
                             w_g1, w_g2, w_g3, w_g4, w_p21, w_p22, w_p23};
    const int rows_[13]  = {1536, 512, 256, 256, 256, 512, 256, 256, 256, 1, 256, 256, 2};
    const int scols_[13] = {512, 512, 514, 256, 256, 256, 512, 256, 256, 256, 512, 256, 256};
    const int dcols_[13] = {512, 512, 576, 256, 256, 256, 512, 256, 256, 256, 512, 256, 256};
    for (int s = 0; s < 13; ++s) {
        ca.src[s] = srcs[s]; ca.rows[s] = rows_[s];
        ca.scols[s] = scols_[s]; ca.dcols[s] = dcols_[s];
    }
    ca.total = (int)wtot;
    cvt_k<<<dim3((unsigned)((wtot + 255) / 256)), dim3(256), 0, stream>>>(ca, wb);

    GemmArgs ga;

    // ---- 2. phi1 chain ----
    ga = {}; ga.Af = encA; ga.lda = 514; ga.klim = 514;
    ga.W = wb + o_p11; ga.ldw = 576; ga.bias = b_p11;
    ga.Cb = Ha; ga.ldc = 256; ga.nK = 9;
    gemm_t<AM_F32U, ACT_ELU, true><<<dim3(512, 2), 256, 0, stream>>>(ga);

    ga = {}; ga.Ab = Ha; ga.lda = 256; ga.W = wb + o_p12; ga.ldw = 256;
    ga.bias = b_p12; ga.Cb = Hb; ga.ldc = 256; ga.nK = 4;
    gemm_t<AM_BF16, ACT_ELU2, true><<<dim3(512, 2), 256, 0, stream>>>(ga);

    ga = {}; ga.Ab = Hb; ga.lda = 256; ga.W = wb + o_p13; ga.ldw = 256;
    ga.bias = b_p13; ga.Cb = Ha; ga.ldc = 256; ga.nK = 4;
    gemm_t<AM_BF16, ACT_ELU, true><<<dim3(512, 2), 256, 0, stream>>>(ga);

    ga = {}; ga.Ab = Ha; ga.lda = 256; ga.W = wb + o_p14; ga.ldw = 256;
    ga.bias = b_p14; ga.Cb = K1; ga.ldc = 512; ga.nK = 4;
    gemm_t<AM_BF16, ACT_NONE, true><<<dim3(512, 4), 256, 0, stream>>>(ga);

    // ---- 3. chunked qkv + attention ----
    const int Mc = 65536 / CH;
    const int gc = 4096 / CH;
    for (int c = 0; c < CH; ++c) {
        ga = {}; ga.Ab = K1 + (long)c * Mc * 512; ga.lda = 512;
        ga.W = wb + o_ain; ga.ldw = 512; ga.bias = b_ain;
        ga.Cb = QKV; ga.ldc = 1536; ga.nK = 8;
        gemm_t<AM_BF16, ACT_NONE, true>
            <<<dim3(Mc / 128, 12), 256, 0, stream>>>(ga);
        attn_k<<<dim3((gc * 2) / 4), 256, 0, stream>>>(QKV, OB + (long)c * gc * 512, gc);
    }

    // ---- 4. key1_mean = obar @ attn_out_w^T + b (f32 out) ----
    ga = {}; ga.Ab = OB; ga.lda = 512; ga.W = wb + o_aout; ga.ldw = 512;
    ga.bias = b_aout; ga.Cf = KM; ga.ldc = 512; ga.nK = 8;
    gemm_t<AM_BF16, ACT_NONE, false><<<dim3(32, 4), 256, 0, stream>>>(ga);

    // ---- 5. g head ----
    ga = {}; ga.Af = KM; ga.lda = 512; ga.W = wb + o_g1; ga.ldw = 512;
    ga.bias = b_g1; ga.Cb = HGa; ga.ldc = 256; ga.nK = 8;
    gemm_t<AM_F32, ACT_ELU, true><<<dim3(32, 2), 256, 0, stream>>>(ga);

    ga = {}; ga.Ab = HGa; ga.lda = 256; ga.W = wb + o_g2; ga.ldw = 256;
    ga.bias = b_g2; ga.Cb = HGb; ga.ldc = 256; ga.nK = 4;
    gemm_t<AM_BF16, ACT_ELU, true><<<dim3(32, 2), 256, 0, stream>>>(ga);

    ga = {}; ga.Ab = HGb; ga.lda = 256; ga.W = wb + o_g3; ga.ldw = 256;
    ga.bias = b_g3; ga.Cb = HGa; ga.ldc = 256; ga.nK = 4;
    gemm_t<AM_BF16, ACT_ELU, true><<<dim3(32, 2), 256, 0, stream>>>(ga);

    qjt_k<<<dim3(16), 256, 0, stream>>>(HGa, wb + o_g4, b_g4, out);

    // ---- 6. phi2 chain (alt_val fused into A staging) ----
    ga = {}; ga.enc = enc; ga.km = KM; ga.key1 = K1;
    ga.W = wb + o_p21; ga.ldw = 512; ga.bias = b_p21;
    ga.Cb = Ha; ga.ldc = 256; ga.nK = 8;
    gemm_t<AM_ALT, ACT_ELU, true><<<dim3(512, 2), 256, 0, stream>>>(ga);

    ga = {}; ga.Ab = Ha; ga.lda = 256; ga.W = wb + o_p22; ga.ldw = 256;
    ga.bias = b_p22; ga.Cb = Hb; ga.ldc = 256; ga.nK = 4;
    gemm_t<AM_BF16, ACT_ELU, true><<<dim3(512, 2), 256, 0, stream>>>(ga);

    altq_k<<<dim3(256), 256, 0, stream>>>(Hb, wb + o_p23, b_p23, out + 4096);
}